// Round 12
// baseline (356.015 us; speedup 1.0000x reference)
//
#include <hip/hip_runtime.h>

#define B_  256
#define T_  512
#define HH  128
#define CC  10
#define CH  9                  // float4 stride per 8-float4 chunk (8 data + 1 pad)
#define BUFQ (CH*8)            // 72 float4 per parity buffer
#define BUFF (BUFQ*4)          // 288 floats per parity buffer

// Native vector type: legal as inline-asm "v" operand (HIP's struct float4 is not).
typedef float f4 __attribute__((ext_vector_type(4)));

__device__ __forceinline__ float fast_rcp(float v) {
#if __has_builtin(__builtin_amdgcn_rcpf)
    return __builtin_amdgcn_rcpf(v);
#else
    return 1.0f / v;
#endif
}

// tanh(z) = sign(z) * (1 - e) / (1 + e),  e = exp(-2|z|).  ~7 VALU, rel err ~1e-6.
__device__ __forceinline__ float fast_tanh(float z) {
    float az = fabsf(z);
    float e  = __expf(-2.0f * az);
    float t  = (1.0f - e) * fast_rcp(1.0f + e);
    return copysignf(t, z);
}

// xor-by-1 / xor-by-2 within quads via DPP quad_perm: single VALU add each,
// instead of __shfl_xor's ds_bpermute (LDS-pipe, ~30cyc serial in the tail).
// (R6 A/B: this + issue-efficiency gain took 388us -> 308us, VALUBusy 70->93%.)
__device__ __forceinline__ float qadd_xor1(float v) {   // [1,0,3,2] = 0xB1
    int s = __builtin_amdgcn_update_dpp(0, __float_as_int(v), 0xB1, 0xF, 0xF, true);
    return v + __int_as_float(s);
}
__device__ __forceinline__ float qadd_xor2(float v) {   // [2,3,0,1] = 0x4E
    int s = __builtin_amdgcn_update_dpp(0, __float_as_int(v), 0x4E, 0xF, 0xF, true);
    return v + __int_as_float(s);
}

// One block per batch row, 512 threads (8 waves = 2 waves/EU).
//   threads [0,256):  layer-1 at step t      (inputs: x_t, h1_{t-1})
//   threads [256,512): layer-2 at step t-1   (inputs: h1_{t-1}, h2_{t-2})
// Per half: lt = tid&255, g = lt>>3 (rows 4g..4g+3), ks = lt&7 (k-chunk of 32 floats).
// Concat input vector (K=256 floats = 8 chunks) in LDS, padded chunk stride CH=9
// float4 (bank-conflict-free broadcast reads). One __syncthreads() per step.
//
// R4/R6/R8 all measured VGPR_Count=92: the allocator AGPR-spills the 128-float
// weight array (write-once, v_accvgpr_read per use ~= +128 VALU/step; measured
// ~340 instr/wave/step vs ~160 intended). waves_per_eu(2,2) raised the budget
// (SGPR changed, dur 308->298) but did NOT move the weights to arch VGPRs.
// Fix: empty asm volatile "+v" pins inside the step force the weight vectors
// into the arch-VGPR class every iteration -> only copy-free allocation is a
// permanent arch home (pressure ~200 < 256, fits).
__global__ __launch_bounds__(512)
__attribute__((amdgpu_waves_per_eu(2, 2)))
void rnn2_fused(
    const float* __restrict__ x,
    const float* __restrict__ Wih0, const float* __restrict__ Whh0,
    const float* __restrict__ bih0, const float* __restrict__ bhh0,
    const float* __restrict__ Wih1, const float* __restrict__ Whh1,
    const float* __restrict__ bih1, const float* __restrict__ bhh1,
    const float* __restrict__ Wfc,  const float* __restrict__ bfc,
    float* __restrict__ out)
{
    const int  tid  = threadIdx.x;
    const int  b    = blockIdx.x;
    const bool lay1 = tid < 256;
    const int  lt   = tid & 255;
    const int  g    = lt >> 3;     // row group: rows 4g..4g+3
    const int  ks   = lt & 7;      // chunk index: concat float4s [8ks, 8ks+8)
    const int  r0   = ks & 3;      // row (4g+r0) this lane finalizes
    const bool wr   = ks < 4;      // writer lanes (one per row)

    // [layer buffer][parity][floats]; layer buf 0 = [x | h1], buf 1 = [h1 | h2]
    __shared__ __align__(16) float sh[2][2][BUFF];

    // ---- weights -> registers (one-time, L2-resident) ----
    // chunk ks<4 multiplies the input half (W_ih), ks>=4 the recurrent half (W_hh)
    const f4* Wi = reinterpret_cast<const f4*>(lay1 ? Wih0 : Wih1);
    const f4* Wh = reinterpret_cast<const f4*>(lay1 ? Whh0 : Whh1);
    const f4* Ws = wr ? Wi : Wh;
    f4 w[4][8];
#pragma unroll
    for (int r = 0; r < 4; ++r)
#pragma unroll
        for (int j = 0; j < 8; ++j)
            w[r][j] = Ws[(4*g + r)*32 + 8*r0 + j];

    const int   hf   = 4*g + r0;
    const float bias = lay1 ? (bih0[hf] + bhh0[hf]) : (bih1[hf] + bhh1[hf]);

    // ---- LDS pointers (all loop-invariant; parity selected at call sites) ----
    const int Lrd = lay1 ? 0 : 1;
    const f4* rbP[2] = {
        reinterpret_cast<const f4*>(&sh[Lrd][0][0]) + CH*ks,
        reinterpret_cast<const f4*>(&sh[Lrd][1][0]) + CH*ks };
    // scalar addr of float 'comp' of chunk c, slot j:  4*(CH*c + j) + comp
    const int aSelf  = 4*(CH*(4 + (g>>3)) + (g&7)) + ks;  // own buffer, h-half
    const int aCross = 4*(CH*(g>>3) + (g&7)) + ks;        // buf1, h1-half (layer-1 only)
    float* wSelfP[2]  = { &sh[Lrd][0][aSelf],  &sh[Lrd][1][aSelf] };
    float* wCrossP[2] = { &sh[1][0][aCross],   &sh[1][1][aCross] };
    f4* xsP[2] = {
        reinterpret_cast<f4*>(&sh[0][0][0]) + CH*(tid>>3) + (tid&7),
        reinterpret_cast<f4*>(&sh[0][1][0]) + CH*(tid>>3) + (tid&7) };

    // ---- init: zero all state, stage x_0, prefetch x_1/x_2 ----
    for (int i = tid; i < 2*2*BUFF; i += 512)
        (&sh[0][0][0])[i] = 0.0f;
    __syncthreads();
    const f4* xb = reinterpret_cast<const f4*>(x) + (size_t)b*T_*32;
    f4 xe = {0.f, 0.f, 0.f, 0.f}, xo = {0.f, 0.f, 0.f, 0.f};
    if (tid < 32) {
        *xsP[0] = xb[0*32 + tid];
        xe = xb[1*32 + tid];
        xo = xb[2*32 + tid];
    }
    __syncthreads();

    auto step = [&](int t, const f4* rp, float* wS, float* wC,
                    f4* xsd, bool l2w, f4& xreg) {
        // Pin all 32 weight vectors to the arch-VGPR class ("v") each step.
        // Empty asm -> zero instructions; defeats the AGPR-spill of the
        // long-lived weight array (the ~128 accvgpr_read/step tax).
        asm volatile("" : "+v"(w[0][0]), "+v"(w[0][1]), "+v"(w[0][2]), "+v"(w[0][3]),
                          "+v"(w[0][4]), "+v"(w[0][5]), "+v"(w[0][6]), "+v"(w[0][7]));
        asm volatile("" : "+v"(w[1][0]), "+v"(w[1][1]), "+v"(w[1][2]), "+v"(w[1][3]),
                          "+v"(w[1][4]), "+v"(w[1][5]), "+v"(w[1][6]), "+v"(w[1][7]));
        asm volatile("" : "+v"(w[2][0]), "+v"(w[2][1]), "+v"(w[2][2]), "+v"(w[2][3]),
                          "+v"(w[2][4]), "+v"(w[2][5]), "+v"(w[2][6]), "+v"(w[2][7]));
        asm volatile("" : "+v"(w[3][0]), "+v"(w[3][1]), "+v"(w[3][2]), "+v"(w[3][3]),
                          "+v"(w[3][4]), "+v"(w[3][5]), "+v"(w[3][6]), "+v"(w[3][7]));

        // stage x_{t+1} (loaded 2 steps ago) into the parity-nxt buffer FIRST:
        // that buffer was fully drained before the previous barrier, so this is
        // race-free, and it issues the next HBM load ~2 steps before its use.
        if (tid < 32) {
            *xsd = xreg;
            xreg = xb[(size_t)min(t + 3, T_ - 1)*32 + tid];
        }

        f4 v[8];
#pragma unroll
        for (int j = 0; j < 8; ++j) v[j] = rp[j];

        float a0 = 0.f, a1 = 0.f, a2 = 0.f, a3 = 0.f;
#pragma unroll
        for (int j = 0; j < 8; ++j) {
            a0 = fmaf(v[j].x, w[0][j].x, a0); a1 = fmaf(v[j].x, w[1][j].x, a1);
            a2 = fmaf(v[j].x, w[2][j].x, a2); a3 = fmaf(v[j].x, w[3][j].x, a3);
            a0 = fmaf(v[j].y, w[0][j].y, a0); a1 = fmaf(v[j].y, w[1][j].y, a1);
            a2 = fmaf(v[j].y, w[2][j].y, a2); a3 = fmaf(v[j].y, w[3][j].y, a3);
            a0 = fmaf(v[j].z, w[0][j].z, a0); a1 = fmaf(v[j].z, w[1][j].z, a1);
            a2 = fmaf(v[j].z, w[2][j].z, a2); a3 = fmaf(v[j].z, w[3][j].z, a3);
            a0 = fmaf(v[j].w, w[0][j].w, a0); a1 = fmaf(v[j].w, w[1][j].w, a1);
            a2 = fmaf(v[j].w, w[2][j].w, a2); a3 = fmaf(v[j].w, w[3][j].w, a3);
        }
        // quad reduce over ks bits 0,1 — DPP quad_perm adds (VALU, not LDS pipe)
        a0 = qadd_xor1(a0); a1 = qadd_xor1(a1);
        a2 = qadd_xor1(a2); a3 = qadd_xor1(a3);
        a0 = qadd_xor2(a0); a1 = qadd_xor2(a1);
        a2 = qadd_xor2(a2); a3 = qadd_xor2(a3);
        // lane picks its row, then combines the two chunk-quads (ih-half + hh-half)
        float s = (r0 & 1) ? ((r0 & 2) ? a3 : a1) : ((r0 & 2) ? a2 : a0);
        s += __shfl_xor(s, 4);
        float th = fast_tanh(s + bias);

        if (wr) {
            if (lay1 || l2w) *wS = th;   // layer-2 skips its (garbage) write at t==0
            if (lay1)        *wC = th;   // h1 also feeds layer-2's input half
        }
        __syncthreads();
    };

    // t = 0 .. 512 (513 iters; layer-2 computes h2_{t-1})
    step(0, rbP[0], wSelfP[1], wCrossP[1], xsP[1], false, xe);
#pragma unroll 1
    for (int i = 0; i < 255; ++i) {
        step(2*i + 1, rbP[1], wSelfP[0], wCrossP[0], xsP[0], true, xo);
        step(2*i + 2, rbP[0], wSelfP[1], wCrossP[1], xsP[1], true, xe);
    }
    step(511, rbP[1], wSelfP[0], wCrossP[0], xsP[0], true, xo);
    step(512, rbP[0], wSelfP[1], wCrossP[1], xsP[1], true, xe);
    // h2_511 now in sh[1][1] h-half (chunks 4..7)

    // ---- classifier on last h2 ----
    if (tid < 4*CC) {
        const int c = tid >> 2, q = tid & 3;
        const f4* hv   = reinterpret_cast<const f4*>(&sh[1][1][0]);
        const f4* Wfc4 = reinterpret_cast<const f4*>(Wfc);
        float a0 = 0.f, a1 = 0.f, a2 = 0.f, a3 = 0.f;
#pragma unroll
        for (int jj = 0; jj < 8; ++jj) {
            f4 v  = hv[CH*(4 + q) + jj];
            f4 ww = Wfc4[c*32 + q*8 + jj];
            a0 = fmaf(v.x, ww.x, a0); a1 = fmaf(v.y, ww.y, a1);
            a2 = fmaf(v.z, ww.z, a2); a3 = fmaf(v.w, ww.w, a3);
        }
        float r = (a0 + a1) + (a2 + a3);
        r += __shfl_xor(r, 1);
        r += __shfl_xor(r, 2);
        if (q == 0) out[b*CC + c] = r + bfc[c];
    }
}

extern "C" void kernel_launch(void* const* d_in, const int* in_sizes, int n_in,
                              void* d_out, int out_size, void* d_ws, size_t ws_size,
                              hipStream_t stream) {
    (void)in_sizes; (void)n_in; (void)d_ws; (void)ws_size; (void)out_size;
    const float* x    = (const float*)d_in[0];
    const float* Wih0 = (const float*)d_in[1];
    const float* Whh0 = (const float*)d_in[2];
    const float* bih0 = (const float*)d_in[3];
    const float* bhh0 = (const float*)d_in[4];
    const float* Wih1 = (const float*)d_in[5];
    const float* Whh1 = (const float*)d_in[6];
    const float* bih1 = (const float*)d_in[7];
    const float* bhh1 = (const float*)d_in[8];
    const float* Wfc  = (const float*)d_in[9];
    const float* bfc  = (const float*)d_in[10];
    float* out = (float*)d_out;

    rnn2_fused<<<B_, 512, 0, stream>>>(x, Wih0, Whh0, bih0, bhh0,
                                       Wih1, Whh1, bih1, bhh1, Wfc, bfc, out);
}